// Round 9
// baseline (188.108 us; speedup 1.0000x reference)
//
#include <hip/hip_runtime.h>

// MSD via MFMA. R16: B operand in registers (front-loaded single-row loads),
// lB LDS tile deleted. A staging + S fusion + reduce unchanged from R13/R15.
// msd[td] = (1/(180*1536)) * sum_i ( S[t] + S[100i] - 2*<x[t],x[100i]> ), t=100i+td
//
// R15 post-mortem: cvt_pk neutral -> pack VALU was NOT the dot residual.
// Eliminated so far: VALU (R15), occupancy>6blk/CU (R12), B-from-global
// in-loop (R14 regressed: per-K vmcnt stalls). Remaining suspect: the B LDS
// round-trip itself -- 6 ds_write + barrier lgkmcnt drain + 6 ds_read_b128
// per thread on the critical chain. Fix: a thread's WHOLE B fragment (6 ks x
// 8 bf16) is one 768B span of one origin row -> 12 global_load_dwordx4 off a
// single vaddr with imm offsets 0..704B, issued BEFORE the barrier (no
// in-loop vmcnt, unlike R14), cvt_pk'd into 24 persistent u32 regs. B rows
// are L2-resident (138 KB/kc-plane, XCD-local via bid%8==kc). LDS 25.6->12.8
// KB. VGPR rises (~90) -> possibly 5 blocks/CU; acceptable per R12.
// ws: 8 dot planes (11.52 MB) + 8 S planes (640 KB) + part (64 KB) = 12.23 MB.
// bf16 cross term only (absmax 7.8e-3 << 4e-2, stable R6-R15).

typedef __attribute__((ext_vector_type(8))) short bf16x8;
typedef __attribute__((ext_vector_type(4))) float f32x4;
typedef __attribute__((ext_vector_type(4))) unsigned u32x4;

#define ROWF   1536
#define NFRAME 20000
#define NORIG  180
#define WIN    20
#define FB     32
#define NFB    625      // 625*32 = 20000 exactly
#define NKC    8        // K planes
#define KC     192      // 1536 / 8
#define NKS    6        // 192 / 32
#define TDMAX  2000
#define PLANE  (NORIG * TDMAX)          // 360000 floats per K-plane
#define SOFF   (NKC * PLANE)            // S planes after dot planes
#define POFF   (SOFF + NKC * NFRAME)    // stage-1 partials after S planes
#define LROW   200                      // 192 bf16 + 8 pad -> 400B row stride
#define SCALE  (1.0f / (1536.0f * 180.0f))

// f32 pair -> packed bf16x2 (RTNE), single VALU op (guide T12 recipe).
static __device__ __forceinline__ unsigned cvtpk(float lo, float hi) {
    unsigned r;
    asm("v_cvt_pk_bf16_f32 %0, %1, %2" : "=v"(r) : "v"(lo), "v"(hi));
    return r;
}

__global__ __launch_bounds__(256)
void msd_dot_kernel(const float* __restrict__ x, float* __restrict__ ws) {
    __shared__ short lA[FB * LROW];   // 12800 B (A tile only)

    const int fb  = blockIdx.x >> 3;    // frame block
    const int kc  = blockIdx.x & 7;     // K plane
    const int t0  = fb * FB;
    const int tid = threadIdx.x;

    const int cmin = t0 / 100;
    int iBase = cmin - (WIN - 1); if (iBase < 0) iBase = 0;

    const int lane = tid & 63;
    const int w    = tid >> 6;   // 4 waves
    const int mt   = w >> 1;     // frame half (16 frames)
    const int nt   = w & 1;      // origin half (16 slots)
    const int m    = lane & 15;
    const int quad = lane >> 4;

    // ---- B fragment: one 768B span of one origin row -> 24 u32 bf16 regs ----
    const int iNom = iBase + 16 * nt + m;
    const int iClp = (iNom < NORIG) ? iNom : (NORIG - 1);
    const float* pB = x + (size_t)(iClp * 100) * ROWF + kc * KC + quad * 8;

    u32x4 bfr[NKS];
    #pragma unroll
    for (int ks = 0; ks < NKS; ++ks) {
        const float4 b0 = *(const float4*)(pB + ks * 32);
        const float4 b1 = *(const float4*)(pB + ks * 32 + 4);
        u32x4 p;
        p[0] = cvtpk(b0.x, b0.y); p[1] = cvtpk(b0.z, b0.w);
        p[2] = cvtpk(b1.x, b1.y); p[3] = cvtpk(b1.z, b1.w);
        bfr[ks] = p;
    }

    // ---- stage A (row-grouped) + inline f32 sumsq ----
    {
        const int r  = tid >> 3;
        const int c8 = tid & 7;
        const float* src = x + (size_t)(t0 + r) * ROWF + kc * KC + c8 * 4;
        short* dst = &lA[r * LROW + c8 * 4];
        float sq = 0.0f;
        #pragma unroll
        for (int it = 0; it < 6; ++it) {
            const float4 v = *(const float4*)(src + it * 32);
            sq += v.x*v.x + v.y*v.y + v.z*v.z + v.w*v.w;
            uint2 p; p.x = cvtpk(v.x, v.y); p.y = cvtpk(v.z, v.w);
            *(uint2*)(dst + it * 32) = p;
        }
        sq += __shfl_xor(sq, 1, 64);
        sq += __shfl_xor(sq, 2, 64);
        sq += __shfl_xor(sq, 4, 64);
        if (c8 == 0)
            ws[SOFF + (size_t)kc * NFRAME + t0 + r] = sq;   // plane-partial S
    }
    __syncthreads();

    // ---- MFMA: A from LDS, B from registers ----
    const short* pa = &lA[(16 * mt + m) * LROW + quad * 8];

    f32x4 acc = {};
    #pragma unroll
    for (int ks = 0; ks < NKS; ++ks) {
        acc = __builtin_amdgcn_mfma_f32_16x16x32_bf16(
            *(const bf16x8*)(pa + ks * 32),
            __builtin_bit_cast(bf16x8, bfr[ks]),
            acc, 0, 0, 0);
    }

    // C/D layout: col = lane&15 (origin slot), row = quad*4 + r (frame-in-tile).
    float* wsp = ws + (size_t)kc * PLANE;
    #pragma unroll
    for (int r = 0; r < 4; ++r) {
        const int j  = 16 * mt + quad * 4 + r;     // frame within block
        const int tt = t0 + j;
        const int c  = tt / 100;
        const int i  = iBase + 16 * nt + m;        // nominal origin of this col
        const int k  = c - i;
        if (k >= 0 && k < WIN && i < NORIG) {
            const int td = tt - 100 * i;           // in [0, 2000)
            wsp[(size_t)i * TDMAX + td] = acc[r];
        }
    }
}

// Stage 1: 256 blocks = (32 td-chunks) x (8 i-chunks). Lanes = consecutive td.
__global__ __launch_bounds__(256)
void msd_reduce1_kernel(const float* __restrict__ ws, float* __restrict__ part) {
    __shared__ float red[4][64];
    const int bx      = blockIdx.x;
    const int tdChunk = bx >> 3;
    const int iChunk  = bx & 7;
    const int lane = threadIdx.x & 63;
    const int w    = threadIdx.x >> 6;
    const int td   = tdChunk * 64 + lane;
    const int tdc  = (td < TDMAX) ? td : (TDMAX - 1);   // clamp, no OOB
    const float* Sp = ws + SOFF;

    const int i0 = iChunk * 23;
    const int i1 = (i0 + 23 < NORIG) ? (i0 + 23) : NORIG;

    float acc = 0.0f;
    for (int i = i0 + w; i < i1; i += 4) {       // ~6 iters per thread
        const int t = 100 * i + tdc;
        float St = 0.0f, Si = 0.0f, D = 0.0f;
        #pragma unroll
        for (int kcp = 0; kcp < NKC; ++kcp) {
            St += Sp[(size_t)kcp * NFRAME + t];            // coalesced
            Si += Sp[(size_t)kcp * NFRAME + 100 * i];      // broadcast
            D  += ws[(size_t)kcp * PLANE + (size_t)i * TDMAX + tdc];  // coalesced
        }
        acc += St + Si - 2.0f * D;
    }
    red[w][lane] = acc;
    __syncthreads();
    if (w == 0 && td < TDMAX)
        part[(size_t)iChunk * TDMAX + td] =
            red[0][lane] + red[1][lane] + red[2][lane] + red[3][lane];
}

// Stage 2: out[td] = SCALE * sum_j part[j][td]. 8 blocks x 256, coalesced.
__global__ __launch_bounds__(256)
void msd_reduce2_kernel(const float* __restrict__ part, float* __restrict__ out) {
    const int td = blockIdx.x * 256 + threadIdx.x;
    if (td >= TDMAX) return;
    float a = 0.0f;
    #pragma unroll
    for (int j = 0; j < 8; ++j)
        a += part[(size_t)j * TDMAX + td];
    out[td] = a * SCALE;
}

extern "C" void kernel_launch(void* const* d_in, const int* in_sizes, int n_in,
                              void* d_out, int out_size, void* d_ws, size_t ws_size,
                              hipStream_t stream) {
    const float* x = (const float*)d_in[0];
    float* out = (float*)d_out;
    float* ws  = (float*)d_ws;    // needs (POFF + 8*2000)*4 = 12.23 MB

    msd_dot_kernel<<<NFB * NKC, 256, 0, stream>>>(x, ws);
    msd_reduce1_kernel<<<256, 256, 0, stream>>>(ws, ws + POFF);
    msd_reduce2_kernel<<<8, 256, 0, stream>>>(ws + POFF, out);
}